// Round 1
// baseline (297.704 us; speedup 1.0000x reference)
//
#include <hip/hip_runtime.h>
#include <math.h>

typedef __bf16 bf16;
typedef __attribute__((ext_vector_type(8))) __bf16 bf16x8;
typedef __attribute__((ext_vector_type(4))) __bf16 bf16x4;
typedef __attribute__((ext_vector_type(4))) float f32x4;

#define INV_SQRT_DK 0.1020620726159658f
#define L2E 1.4426950408889634f

// ---------------- convert x: f32 -> bf16 ----------------
__global__ __launch_bounds__(256) void cvt_x(const float* __restrict__ x, bf16* __restrict__ xb) {
    size_t i = ((size_t)blockIdx.x * 256 + threadIdx.x) * 4;
    f32x4 v = *(const f32x4*)(x + i);
    bf16x4 o;
    o[0] = (bf16)v[0]; o[1] = (bf16)v[1]; o[2] = (bf16)v[2]; o[3] = (bf16)v[3];
    *(bf16x4*)(xb + i) = o;
}

// ---------------- transpose + convert weights: W (K,N) f32 -> Wt (N,K) bf16 ----------------
struct WArgs { const float* w[4]; };

__global__ __launch_bounds__(256) void transpose_w(WArgs wa, bf16* __restrict__ out) {
    __shared__ float t[32][33];
    const int z = blockIdx.z;
    const float* __restrict__ W = wa.w[z];
    bf16* __restrict__ Wt = out + (size_t)z * 589824;
    int k0 = blockIdx.x * 32, n0 = blockIdx.y * 32;
    int tx = threadIdx.x, ty = threadIdx.y; // 32 x 8
#pragma unroll
    for (int j = 0; j < 4; ++j)
        t[ty + j * 8][tx] = W[(size_t)(k0 + ty + j * 8) * 768 + n0 + tx];
    __syncthreads();
#pragma unroll
    for (int j = 0; j < 4; ++j)
        Wt[(size_t)(n0 + ty + j * 8) * 768 + k0 + tx] = (bf16)t[tx][ty + j * 8];
}

// ---------------- GEMM: C[M,768] = A[M,768](bf16) @ W[768,768] + bias ----------------
// A row-major; weights given transposed Wt[n][k]. 128x128 tile, BK=64, 4 waves (2x2),
// each wave 64x64 via 4x4 frags of 16x16x32 MFMA. XOR-swizzled LDS (T2-style).
struct GemmArgs {
    const bf16* Bt[3];
    const float* bias[3];
    void* out[3];
};

template <bool F32OUT>
__global__ __launch_bounds__(256, 2) void gemm_kernel(const bf16* __restrict__ A, GemmArgs ga) {
    __shared__ __align__(16) bf16 As[128 * 64];
    __shared__ __align__(16) bf16 Bs[128 * 64];
    const int z = blockIdx.z;
    const bf16* __restrict__ Bt = ga.Bt[z];
    const int m0 = blockIdx.x * 128;
    const int n0 = blockIdx.y * 128;
    const int tid = threadIdx.x;
    const int lane = tid & 63, l15 = lane & 15, lq = lane >> 4;
    const int wid = tid >> 6;
    const int wm = (wid >> 1) * 64, wn = (wid & 1) * 64;

    f32x4 acc[4][4] = {};

    const int srow = tid >> 1;        // 0..127
    const int sc0 = (tid & 1) * 4;    // chunk 0-3 or 4-7 (16B chunks of a 128B row)
    const bf16* __restrict__ Arow = A + (size_t)(m0 + srow) * 768;
    const bf16* __restrict__ Brow = Bt + (size_t)(n0 + srow) * 768;
    const int swz = srow & 7;

    for (int ks = 0; ks < 768; ks += 64) {
#pragma unroll
        for (int i = 0; i < 4; ++i) {
            int c = sc0 + i;
            bf16x8 av = *(const bf16x8*)(Arow + ks + c * 8);
            bf16x8 bv = *(const bf16x8*)(Brow + ks + c * 8);
            int sc = c ^ swz;
            *(bf16x8*)(As + srow * 64 + sc * 8) = av;
            *(bf16x8*)(Bs + srow * 64 + sc * 8) = bv;
        }
        __syncthreads();
#pragma unroll
        for (int kk = 0; kk < 2; ++kk) {
            bf16x8 af[4], bfr[4];
#pragma unroll
            for (int f = 0; f < 4; ++f) {
                int ar = wm + f * 16 + l15;
                int ac = (kk * 4 + lq) ^ (ar & 7);
                af[f] = *(const bf16x8*)(As + ar * 64 + ac * 8);
                int br = wn + f * 16 + l15;
                int bc = (kk * 4 + lq) ^ (br & 7);
                bfr[f] = *(const bf16x8*)(Bs + br * 64 + bc * 8);
            }
#pragma unroll
            for (int mf = 0; mf < 4; ++mf)
#pragma unroll
                for (int nf = 0; nf < 4; ++nf)
                    acc[mf][nf] = __builtin_amdgcn_mfma_f32_16x16x32_bf16(af[mf], bfr[nf], acc[mf][nf], 0, 0, 0);
        }
        __syncthreads();
    }
    const float* __restrict__ bias = ga.bias[z];
#pragma unroll
    for (int nf = 0; nf < 4; ++nf) {
        int col = n0 + wn + nf * 16 + l15;
        float bv = bias[col];
#pragma unroll
        for (int mf = 0; mf < 4; ++mf) {
            int rbase = m0 + wm + mf * 16 + lq * 4;
#pragma unroll
            for (int i = 0; i < 4; ++i) {
                float v = acc[mf][nf][i] + bv;
                if constexpr (F32OUT)
                    ((float*)ga.out[z])[(size_t)(rbase + i) * 768 + col] = v;
                else
                    ((bf16*)ga.out[z])[(size_t)(rbase + i) * 768 + col] = (bf16)v;
            }
        }
    }
}

// ---------------- V transpose per head-group: V[g][kv][d] -> Vt[g][d][kv] ----------------
__global__ __launch_bounds__(256) void transpose_v(const bf16* __restrict__ V, bf16* __restrict__ Vt) {
    __shared__ unsigned short t[64 * 97];
    const int g = blockIdx.y;
    const int kv0 = blockIdx.x * 64;
    const unsigned short* __restrict__ Vg = (const unsigned short*)V + (size_t)g * 98304;
    unsigned short* __restrict__ Vtg = (unsigned short*)Vt + (size_t)g * 98304;
    const int tid = threadIdx.x;
#pragma unroll
    for (int p = 0; p < 24; ++p) {
        int id = tid + p * 256;  // 0..6143
        int row = id / 96, col = id % 96;
        t[row * 97 + col] = Vg[(size_t)(kv0 + row) * 96 + col];
    }
    __syncthreads();
#pragma unroll
    for (int p = 0; p < 24; ++p) {
        int id = tid + p * 256;
        int d = id >> 6, j = id & 63;
        Vtg[(size_t)d * 1024 + kv0 + j] = t[j * 97 + d];
    }
}

// ---------------- fused flash attention over one (b,h) group ----------------
// Q,K: [g][1024][96] bf16 contiguous. Vt: [g][96][1024]. Out: [g][1024][96] bf16.
// Block: 256 thr = 4 waves; block handles 128 q-rows, each wave 32 (2 m-frags).
// KV tiles of 128. P routed through per-wave-private LDS (no barriers needed).
__global__ __launch_bounds__(256, 2) void attn_kernel(const bf16* __restrict__ Q, const bf16* __restrict__ K,
                                                      const bf16* __restrict__ Vt, bf16* __restrict__ AO) {
    __shared__ __align__(16) bf16 Plds[128 * 136];
    const int g = blockIdx.y;
    const int q0 = blockIdx.x * 128;
    const int tid = threadIdx.x;
    const int lane = tid & 63, l15 = lane & 15, lq = lane >> 4;
    const int wid = tid >> 6;
    const int wq = wid * 32;
    const size_t gbase = (size_t)g * 98304;
    const bf16* __restrict__ Qg = Q + gbase;
    const bf16* __restrict__ Kg = K + gbase;
    const bf16* __restrict__ Vg = Vt + gbase;
    bf16* __restrict__ Og = AO + gbase;

    // Q fragments [m][kk] (rows q0+wq+m*16+l15, k = kk*32+lq*8)
    bf16x8 qf[2][3];
#pragma unroll
    for (int m = 0; m < 2; ++m)
#pragma unroll
        for (int kk = 0; kk < 3; ++kk)
            qf[m][kk] = *(const bf16x8*)(Qg + (size_t)(q0 + wq + m * 16 + l15) * 96 + kk * 32 + lq * 8);

    f32x4 o[2][6] = {};
    float mrun[2][4], lrun[2][4];
#pragma unroll
    for (int m = 0; m < 2; ++m)
#pragma unroll
        for (int r = 0; r < 4; ++r) { mrun[m][r] = -INFINITY; lrun[m][r] = 0.f; }

    for (int kt = 0; kt < 8; ++kt) {
        const int kv0 = kt * 128;
        f32x4 s[2][8] = {};
#pragma unroll
        for (int kk = 0; kk < 3; ++kk) {
            bf16x8 kf[8];
#pragma unroll
            for (int n = 0; n < 8; ++n)
                kf[n] = *(const bf16x8*)(Kg + (size_t)(kv0 + n * 16 + l15) * 96 + kk * 32 + lq * 8);
#pragma unroll
            for (int m = 0; m < 2; ++m)
#pragma unroll
                for (int n = 0; n < 8; ++n)
                    s[m][n] = __builtin_amdgcn_mfma_f32_16x16x32_bf16(qf[m][kk], kf[n], s[m][n], 0, 0, 0);
        }
        // scale
#pragma unroll
        for (int m = 0; m < 2; ++m)
#pragma unroll
            for (int n = 0; n < 8; ++n)
                s[m][n] = s[m][n] * INV_SQRT_DK;
        // online softmax per q-row (row r of frag m lives in 16-lane group lq, reg r)
#pragma unroll
        for (int m = 0; m < 2; ++m) {
#pragma unroll
            for (int r = 0; r < 4; ++r) {
                float mx = s[m][0][r];
#pragma unroll
                for (int n = 1; n < 8; ++n) mx = fmaxf(mx, s[m][n][r]);
#pragma unroll
                for (int off = 1; off < 16; off <<= 1) mx = fmaxf(mx, __shfl_xor(mx, off));
                float newm = fmaxf(mrun[m][r], mx);
                float alpha = exp2f((mrun[m][r] - newm) * L2E);
                mrun[m][r] = newm;
                float rs = 0.f;
#pragma unroll
                for (int n = 0; n < 8; ++n) {
                    float p = exp2f((s[m][n][r] - newm) * L2E);
                    s[m][n][r] = p;
                    rs += p;
                }
#pragma unroll
                for (int off = 1; off < 16; off <<= 1) rs += __shfl_xor(rs, off);
                lrun[m][r] = lrun[m][r] * alpha + rs;
#pragma unroll
                for (int n = 0; n < 6; ++n) o[m][n][r] *= alpha;
            }
        }
        // P -> LDS (per-wave private rows, no barrier needed)
#pragma unroll
        for (int m = 0; m < 2; ++m)
#pragma unroll
            for (int r = 0; r < 4; ++r) {
                int prow = wq + m * 16 + lq * 4 + r;
#pragma unroll
                for (int n = 0; n < 8; ++n)
                    Plds[prow * 136 + n * 16 + l15] = (bf16)s[m][n][r];
            }
        // O += P @ V
#pragma unroll
        for (int kk = 0; kk < 4; ++kk) {
            bf16x8 pf[2], vf[6];
#pragma unroll
            for (int m = 0; m < 2; ++m)
                pf[m] = *(const bf16x8*)(Plds + (wq + m * 16 + l15) * 136 + kk * 32 + lq * 8);
#pragma unroll
            for (int n = 0; n < 6; ++n)
                vf[n] = *(const bf16x8*)(Vg + (size_t)(n * 16 + l15) * 1024 + kv0 + kk * 32 + lq * 8);
#pragma unroll
            for (int m = 0; m < 2; ++m)
#pragma unroll
                for (int n = 0; n < 6; ++n)
                    o[m][n] = __builtin_amdgcn_mfma_f32_16x16x32_bf16(pf[m], vf[n], o[m][n], 0, 0, 0);
        }
    }
    // epilogue: normalize + store bf16
#pragma unroll
    for (int m = 0; m < 2; ++m)
#pragma unroll
        for (int r = 0; r < 4; ++r) {
            float inv = 1.0f / lrun[m][r];
            int row = q0 + wq + m * 16 + lq * 4 + r;
#pragma unroll
            for (int n = 0; n < 6; ++n)
                Og[(size_t)row * 96 + n * 16 + l15] = (bf16)(o[m][n][r] * inv);
        }
}

// ---------------- launch ----------------
extern "C" void kernel_launch(void* const* d_in, const int* in_sizes, int n_in,
                              void* d_out, int out_size, void* d_ws, size_t ws_size,
                              hipStream_t stream) {
    const float* x  = (const float*)d_in[0];
    const float* Wq = (const float*)d_in[1];
    const float* bq = (const float*)d_in[2];
    const float* Wk = (const float*)d_in[3];
    const float* bk = (const float*)d_in[4];
    const float* Wv = (const float*)d_in[5];
    const float* bv = (const float*)d_in[6];
    const float* Wp = (const float*)d_in[7];
    const float* bp = (const float*)d_in[8];

    char* ws = (char*)d_ws;
    bf16* xb  = (bf16*)(ws);                  // 25,165,824 B; reused as AO after QKV GEMM
    bf16* wt  = (bf16*)(ws + 25165824);       // 4 x 1,179,648 B (Wq^T, Wk^T, Wv^T, Wp^T)
    bf16* Qb  = (bf16*)(ws + 29884416);
    bf16* Kb  = (bf16*)(ws + 55050240);
    bf16* Vb  = (bf16*)(ws + 80216064);
    bf16* Vtb = (bf16*)(ws + 105381888);      // end: 130,547,712 B
    bf16* AO  = xb;

    cvt_x<<<12288, 256, 0, stream>>>(x, xb);

    WArgs wa;
    wa.w[0] = Wq; wa.w[1] = Wk; wa.w[2] = Wv; wa.w[3] = Wp;
    transpose_w<<<dim3(24, 24, 4), dim3(32, 8), 0, stream>>>(wa, wt);

    GemmArgs g1{};
    g1.Bt[0] = wt;            g1.Bt[1] = wt + 589824;  g1.Bt[2] = wt + 2 * 589824;
    g1.bias[0] = bq;          g1.bias[1] = bk;         g1.bias[2] = bv;
    g1.out[0] = Qb;           g1.out[1] = Kb;          g1.out[2] = Vb;
    gemm_kernel<false><<<dim3(128, 6, 3), 256, 0, stream>>>(xb, g1);

    transpose_v<<<dim3(16, 128), 256, 0, stream>>>(Vb, Vtb);

    attn_kernel<<<dim3(8, 128), 256, 0, stream>>>(Qb, Kb, Vtb, AO);

    GemmArgs g2{};
    g2.Bt[0] = wt + 3 * 589824; g2.bias[0] = bp; g2.out[0] = (void*)d_out;
    g2.Bt[1] = g2.Bt[0]; g2.Bt[2] = g2.Bt[0];
    g2.bias[1] = bp; g2.bias[2] = bp;
    g2.out[1] = g2.out[0]; g2.out[2] = g2.out[0];
    gemm_kernel<true><<<dim3(128, 6, 1), 256, 0, stream>>>(AO, g2);
}

// Round 2
// 278.849 us; speedup vs baseline: 1.0676x; 1.0676x over previous
//
#include <hip/hip_runtime.h>
#include <math.h>

typedef __bf16 bf16;
typedef __attribute__((ext_vector_type(8))) __bf16 bf16x8;
typedef __attribute__((ext_vector_type(4))) __bf16 bf16x4;
typedef __attribute__((ext_vector_type(4))) float f32x4;
typedef __attribute__((ext_vector_type(16))) float f32x16;

#define CE 0.14724445f  /* (1/sqrt(96)) * log2(e) */

// ---------------- convert x: f32 -> bf16 ----------------
__global__ __launch_bounds__(256) void cvt_x(const float* __restrict__ x, bf16* __restrict__ xb) {
    size_t i = ((size_t)blockIdx.x * 256 + threadIdx.x) * 4;
    f32x4 v = *(const f32x4*)(x + i);
    bf16x4 o;
    o[0] = (bf16)v[0]; o[1] = (bf16)v[1]; o[2] = (bf16)v[2]; o[3] = (bf16)v[3];
    *(bf16x4*)(xb + i) = o;
}

// ---------------- transpose + convert weights: W (K,N) f32 -> Wt (N,K) bf16 ----------------
struct WArgs { const float* w[4]; };

__global__ __launch_bounds__(256) void transpose_w(WArgs wa, bf16* __restrict__ out) {
    __shared__ float t[32][33];
    const int z = blockIdx.z;
    const float* __restrict__ W = wa.w[z];
    bf16* __restrict__ Wt = out + (size_t)z * 589824;
    int k0 = blockIdx.x * 32, n0 = blockIdx.y * 32;
    int tx = threadIdx.x, ty = threadIdx.y; // 32 x 8
#pragma unroll
    for (int j = 0; j < 4; ++j)
        t[ty + j * 8][tx] = W[(size_t)(k0 + ty + j * 8) * 768 + n0 + tx];
    __syncthreads();
#pragma unroll
    for (int j = 0; j < 4; ++j)
        Wt[(size_t)(n0 + ty + j * 8) * 768 + k0 + tx] = (bf16)t[tx][ty + j * 8];
}

// ---------------- GEMM: C[M,768] = A[M,768](bf16) @ W[768,768] + bias ----------------
struct GemmArgs {
    const bf16* Bt[3];
    const float* bias[3];
    void* out[3];
};

template <bool F32OUT>
__global__ __launch_bounds__(256, 2) void gemm_kernel(const bf16* __restrict__ A, GemmArgs ga) {
    __shared__ __align__(16) bf16 As[128 * 64];
    __shared__ __align__(16) bf16 Bs[128 * 64];
    const int z = blockIdx.z;
    const bf16* __restrict__ Bt = ga.Bt[z];
    const int m0 = blockIdx.x * 128;
    const int n0 = blockIdx.y * 128;
    const int tid = threadIdx.x;
    const int lane = tid & 63, l15 = lane & 15, lq = lane >> 4;
    const int wid = tid >> 6;
    const int wm = (wid >> 1) * 64, wn = (wid & 1) * 64;

    f32x4 acc[4][4] = {};

    const int srow = tid >> 1;
    const int sc0 = (tid & 1) * 4;
    const bf16* __restrict__ Arow = A + (size_t)(m0 + srow) * 768;
    const bf16* __restrict__ Brow = Bt + (size_t)(n0 + srow) * 768;
    const int swz = srow & 7;

    for (int ks = 0; ks < 768; ks += 64) {
#pragma unroll
        for (int i = 0; i < 4; ++i) {
            int c = sc0 + i;
            bf16x8 av = *(const bf16x8*)(Arow + ks + c * 8);
            bf16x8 bv = *(const bf16x8*)(Brow + ks + c * 8);
            int sc = c ^ swz;
            *(bf16x8*)(As + srow * 64 + sc * 8) = av;
            *(bf16x8*)(Bs + srow * 64 + sc * 8) = bv;
        }
        __syncthreads();
#pragma unroll
        for (int kk = 0; kk < 2; ++kk) {
            bf16x8 af[4], bfr[4];
#pragma unroll
            for (int f = 0; f < 4; ++f) {
                int ar = wm + f * 16 + l15;
                int ac = (kk * 4 + lq) ^ (ar & 7);
                af[f] = *(const bf16x8*)(As + ar * 64 + ac * 8);
                int br = wn + f * 16 + l15;
                int bc = (kk * 4 + lq) ^ (br & 7);
                bfr[f] = *(const bf16x8*)(Bs + br * 64 + bc * 8);
            }
#pragma unroll
            for (int mf = 0; mf < 4; ++mf)
#pragma unroll
                for (int nf = 0; nf < 4; ++nf)
                    acc[mf][nf] = __builtin_amdgcn_mfma_f32_16x16x32_bf16(af[mf], bfr[nf], acc[mf][nf], 0, 0, 0);
        }
        __syncthreads();
    }
    const float* __restrict__ bias = ga.bias[z];
#pragma unroll
    for (int nf = 0; nf < 4; ++nf) {
        int col = n0 + wn + nf * 16 + l15;
        float bv = bias[col];
#pragma unroll
        for (int mf = 0; mf < 4; ++mf) {
            int rbase = m0 + wm + mf * 16 + lq * 4;
#pragma unroll
            for (int i = 0; i < 4; ++i) {
                float v = acc[mf][nf][i] + bv;
                if constexpr (F32OUT)
                    ((float*)ga.out[z])[(size_t)(rbase + i) * 768 + col] = v;
                else
                    ((bf16*)ga.out[z])[(size_t)(rbase + i) * 768 + col] = (bf16)v;
            }
        }
    }
}

// ---------------- V transpose per head-group: V[g][kv][d] -> Vt[g][d][kv] ----------------
__global__ __launch_bounds__(256) void transpose_v(const bf16* __restrict__ V, bf16* __restrict__ Vt) {
    __shared__ unsigned short t[64 * 97];
    const int g = blockIdx.y;
    const int kv0 = blockIdx.x * 64;
    const unsigned short* __restrict__ Vg = (const unsigned short*)V + (size_t)g * 98304;
    unsigned short* __restrict__ Vtg = (unsigned short*)Vt + (size_t)g * 98304;
    const int tid = threadIdx.x;
#pragma unroll
    for (int p = 0; p < 24; ++p) {
        int id = tid + p * 256;
        int row = id / 96, col = id % 96;
        t[row * 97 + col] = Vg[(size_t)(kv0 + row) * 96 + col];
    }
    __syncthreads();
#pragma unroll
    for (int p = 0; p < 24; ++p) {
        int id = tid + p * 256;
        int d = id >> 6, j = id & 63;
        Vtg[(size_t)d * 1024 + kv0 + j] = t[j * 97 + d];
    }
}

// ---------------- helpers for in-register P ----------------
static __device__ inline int pk2(float a, float b) {
    union { __bf16 h[2]; int w; } u;
    u.h[0] = (__bf16)a; u.h[1] = (__bf16)b;
    return u.w;
}

// Build one 16-k B-fragment (K=16 step) from 8 per-lane P values whose kv offsets
// are {0..3}+4*hi (p0..p3) and {8..11}+4*hi (p4..p7). Needed layout: elem j -> kv hi*8+j.
static __device__ inline bf16x8 pack_step(float p0, float p1, float p2, float p3,
                                          float p4, float p5, float p6, float p7, int hi) {
    int A0 = pk2(p0, p1), A1 = pk2(p2, p3);   // kv {0,1}+4hi, {2,3}+4hi
    int B0 = pk2(p4, p5), B1 = pk2(p6, p7);   // kv {8,9}+4hi, {10,11}+4hi
    int t0 = hi ? A0 : B0;
    int t1 = hi ? A1 : B1;
    int x0 = __shfl_xor(t0, 32);  // hi=0 gets partner A0 (kv{4,5}); hi=1 gets partner B0 (kv{8,9})
    int x1 = __shfl_xor(t1, 32);
    union { int w[4]; bf16x8 v; } u;
    u.w[0] = hi ? x0 : A0;   // kv {0,1}+8hi
    u.w[1] = hi ? x1 : A1;   // kv {2,3}+8hi
    u.w[2] = hi ? B0 : x0;   // kv {4,5}+8hi
    u.w[3] = hi ? B1 : x1;   // kv {6,7}+8hi
    return u.v;
}

// ---------------- fused flash attention, swapped-QK^T, in-register P ----------------
// Q,K: [g][1024][96] bf16. Vt: [g][96][1024]. Out: [g][1024][96].
// 4 waves/block, each wave owns 32 q-rows (one q per lane-pair). S^T = mfma(K, Q),
// softmax lane-local (+1 lane^32 exchange), P packed in-register, O^T = mfma(V^T, P^T).
// No LDS, no barriers.
__global__ __launch_bounds__(256) void attn_kernel(const bf16* __restrict__ Q, const bf16* __restrict__ K,
                                                   const bf16* __restrict__ Vt, bf16* __restrict__ AO) {
    const int g = blockIdx.y;
    const int q0 = blockIdx.x * 128;
    const int tid = threadIdx.x;
    const int lane = tid & 63;
    const int l31 = lane & 31;
    const int hi = lane >> 5;
    const int wid = tid >> 6;
    const int qrow = q0 + wid * 32 + l31;
    const size_t gbase = (size_t)g * 98304;
    const bf16* __restrict__ Qg = Q + gbase;
    const bf16* __restrict__ Kg = K + gbase;
    const bf16* __restrict__ Vg = Vt + gbase;  // [96][1024]
    bf16* __restrict__ Og = AO + gbase;

    // Q as B-fragments: qf[kk], k = kk*16 + hi*8 + j
    bf16x8 qf[6];
#pragma unroll
    for (int kk = 0; kk < 6; ++kk)
        qf[kk] = *(const bf16x8*)(Qg + (size_t)qrow * 96 + kk * 16 + hi * 8);

    f32x16 o[3] = {};  // O^T accumulators: d-frags of 32; col = q = l31
    float mrun = -INFINITY, lrun = 0.f;

    for (int kt = 0; kt < 16; ++kt) {
        const int kv0 = kt * 64;
        // S^T = K @ Q^T : two 32-kv fragments
        f32x16 s0 = {}, s1 = {};
#pragma unroll
        for (int kk = 0; kk < 6; ++kk) {
            bf16x8 k0 = *(const bf16x8*)(Kg + (size_t)(kv0 + l31) * 96 + kk * 16 + hi * 8);
            bf16x8 k1 = *(const bf16x8*)(Kg + (size_t)(kv0 + 32 + l31) * 96 + kk * 16 + hi * 8);
            s0 = __builtin_amdgcn_mfma_f32_32x32x16_bf16(k0, qf[kk], s0, 0, 0, 0);
            s1 = __builtin_amdgcn_mfma_f32_32x32x16_bf16(k1, qf[kk], s1, 0, 0, 0);
        }
        // lane-local row max over 32 values + partner exchange (raw logit domain)
        float mx = s0[0];
#pragma unroll
        for (int r = 1; r < 16; ++r) mx = fmaxf(mx, s0[r]);
#pragma unroll
        for (int r = 0; r < 16; ++r) mx = fmaxf(mx, s1[r]);
        mx = fmaxf(mx, __shfl_xor(mx, 32));
        float newm = fmaxf(mrun, mx);
        float alpha = __builtin_amdgcn_exp2f(CE * (mrun - newm));
        mrun = newm;
        float lsum = 0.f;
#pragma unroll
        for (int r = 0; r < 16; ++r) {
            float p = __builtin_amdgcn_exp2f(CE * (s0[r] - newm));
            s0[r] = p; lsum += p;
        }
#pragma unroll
        for (int r = 0; r < 16; ++r) {
            float p = __builtin_amdgcn_exp2f(CE * (s1[r] - newm));
            s1[r] = p; lsum += p;
        }
        lsum += __shfl_xor(lsum, 32);
        lrun = lrun * alpha + lsum;
#pragma unroll
        for (int df = 0; df < 3; ++df)
#pragma unroll
            for (int r = 0; r < 16; ++r) o[df][r] *= alpha;

        // P -> packed bf16 B-fragments (in-register), then O^T += V^T @ P^T
        bf16x8 pb0 = pack_step(s0[0], s0[1], s0[2], s0[3], s0[4], s0[5], s0[6], s0[7], hi);
        bf16x8 pb1 = pack_step(s0[8], s0[9], s0[10], s0[11], s0[12], s0[13], s0[14], s0[15], hi);
#pragma unroll
        for (int df = 0; df < 3; ++df) {
            const bf16* vrow = Vg + (size_t)(df * 32 + l31) * 1024 + kv0 + hi * 8;
            bf16x8 v0 = *(const bf16x8*)(vrow);
            bf16x8 v1 = *(const bf16x8*)(vrow + 16);
            o[df] = __builtin_amdgcn_mfma_f32_32x32x16_bf16(v0, pb0, o[df], 0, 0, 0);
            o[df] = __builtin_amdgcn_mfma_f32_32x32x16_bf16(v1, pb1, o[df], 0, 0, 0);
        }
        bf16x8 pb2 = pack_step(s1[0], s1[1], s1[2], s1[3], s1[4], s1[5], s1[6], s1[7], hi);
        bf16x8 pb3 = pack_step(s1[8], s1[9], s1[10], s1[11], s1[12], s1[13], s1[14], s1[15], hi);
#pragma unroll
        for (int df = 0; df < 3; ++df) {
            const bf16* vrow = Vg + (size_t)(df * 32 + l31) * 1024 + kv0 + 32 + hi * 8;
            bf16x8 v2 = *(const bf16x8*)(vrow);
            bf16x8 v3 = *(const bf16x8*)(vrow + 16);
            o[df] = __builtin_amdgcn_mfma_f32_32x32x16_bf16(v2, pb2, o[df], 0, 0, 0);
            o[df] = __builtin_amdgcn_mfma_f32_32x32x16_bf16(v3, pb3, o[df], 0, 0, 0);
        }
    }

    // epilogue: O[q][d] = O^T[d][q] / lrun
    float inv = 1.0f / lrun;
#pragma unroll
    for (int df = 0; df < 3; ++df)
#pragma unroll
        for (int rq = 0; rq < 4; ++rq) {
            bf16x4 ov;
#pragma unroll
            for (int j = 0; j < 4; ++j) ov[j] = (bf16)(o[df][rq * 4 + j] * inv);
            *(bf16x4*)(Og + (size_t)qrow * 96 + df * 32 + rq * 8 + hi * 4) = ov;
        }
}

// ---------------- launch ----------------
extern "C" void kernel_launch(void* const* d_in, const int* in_sizes, int n_in,
                              void* d_out, int out_size, void* d_ws, size_t ws_size,
                              hipStream_t stream) {
    const float* x  = (const float*)d_in[0];
    const float* Wq = (const float*)d_in[1];
    const float* bq = (const float*)d_in[2];
    const float* Wk = (const float*)d_in[3];
    const float* bk = (const float*)d_in[4];
    const float* Wv = (const float*)d_in[5];
    const float* bv = (const float*)d_in[6];
    const float* Wp = (const float*)d_in[7];
    const float* bp = (const float*)d_in[8];

    char* ws = (char*)d_ws;
    bf16* xb  = (bf16*)(ws);                  // reused as AO after QKV GEMM
    bf16* wt  = (bf16*)(ws + 25165824);       // 4 x 1,179,648 B
    bf16* Qb  = (bf16*)(ws + 29884416);
    bf16* Kb  = (bf16*)(ws + 55050240);
    bf16* Vb  = (bf16*)(ws + 80216064);
    bf16* Vtb = (bf16*)(ws + 105381888);
    bf16* AO  = xb;

    cvt_x<<<12288, 256, 0, stream>>>(x, xb);

    WArgs wa;
    wa.w[0] = Wq; wa.w[1] = Wk; wa.w[2] = Wv; wa.w[3] = Wp;
    transpose_w<<<dim3(24, 24, 4), dim3(32, 8), 0, stream>>>(wa, wt);

    GemmArgs g1{};
    g1.Bt[0] = wt;            g1.Bt[1] = wt + 589824;  g1.Bt[2] = wt + 2 * 589824;
    g1.bias[0] = bq;          g1.bias[1] = bk;         g1.bias[2] = bv;
    g1.out[0] = Qb;           g1.out[1] = Kb;          g1.out[2] = Vb;
    gemm_kernel<false><<<dim3(128, 6, 3), 256, 0, stream>>>(xb, g1);

    transpose_v<<<dim3(16, 128), 256, 0, stream>>>(Vb, Vtb);

    attn_kernel<<<dim3(8, 128), 256, 0, stream>>>(Qb, Kb, Vtb, AO);

    GemmArgs g2{};
    g2.Bt[0] = wt + 3 * 589824; g2.bias[0] = bp; g2.out[0] = (void*)d_out;
    g2.Bt[1] = g2.Bt[0]; g2.Bt[2] = g2.Bt[0];
    g2.bias[1] = bp; g2.bias[2] = bp;
    g2.out[1] = g2.out[0]; g2.out[2] = g2.out[0];
    gemm_kernel<true><<<dim3(128, 6, 1), 256, 0, stream>>>(AO, g2);
}

// Round 3
// 228.965 us; speedup vs baseline: 1.3002x; 1.2179x over previous
//
#include <hip/hip_runtime.h>
#include <math.h>

typedef __bf16 bf16;
typedef __attribute__((ext_vector_type(8))) __bf16 bf16x8;
typedef __attribute__((ext_vector_type(4))) __bf16 bf16x4;
typedef __attribute__((ext_vector_type(4))) float f32x4;
typedef __attribute__((ext_vector_type(16))) float f32x16;

#define CE 0.14724445f  /* (1/sqrt(96)) * log2(e) */

// ---------------- convert x: f32 -> bf16 ----------------
__global__ __launch_bounds__(256) void cvt_x(const float* __restrict__ x, bf16* __restrict__ xb) {
    size_t i = ((size_t)blockIdx.x * 256 + threadIdx.x) * 4;
    f32x4 v = *(const f32x4*)(x + i);
    bf16x4 o;
    o[0] = (bf16)v[0]; o[1] = (bf16)v[1]; o[2] = (bf16)v[2]; o[3] = (bf16)v[3];
    *(bf16x4*)(xb + i) = o;
}

// ---------------- transpose + convert weights: W (K,N) f32 -> Wt (N,K) bf16 ----------------
struct WArgs { const float* w[4]; };

__global__ __launch_bounds__(256) void transpose_w(WArgs wa, bf16* __restrict__ out) {
    __shared__ float t[32][33];
    const int z = blockIdx.z;
    const float* __restrict__ W = wa.w[z];
    bf16* __restrict__ Wt = out + (size_t)z * 589824;
    int k0 = blockIdx.x * 32, n0 = blockIdx.y * 32;
    int tx = threadIdx.x, ty = threadIdx.y; // 32 x 8
#pragma unroll
    for (int j = 0; j < 4; ++j)
        t[ty + j * 8][tx] = W[(size_t)(k0 + ty + j * 8) * 768 + n0 + tx];
    __syncthreads();
#pragma unroll
    for (int j = 0; j < 4; ++j)
        Wt[(size_t)(n0 + ty + j * 8) * 768 + k0 + tx] = (bf16)t[tx][ty + j * 8];
}

// ---------------- GEMM: C[M,768] = A[M,768](bf16) @ W[768,768] + bias ----------------
struct GemmArgs {
    const bf16* Bt[3];
    const float* bias[3];
    void* out[3];
};

template <bool F32OUT>
__global__ __launch_bounds__(256, 2) void gemm_kernel(const bf16* __restrict__ A, GemmArgs ga) {
    __shared__ __align__(16) bf16 As[128 * 64];
    __shared__ __align__(16) bf16 Bs[128 * 64];
    const int z = blockIdx.z;
    const bf16* __restrict__ Bt = ga.Bt[z];
    const int m0 = blockIdx.x * 128;
    const int n0 = blockIdx.y * 128;
    const int tid = threadIdx.x;
    const int lane = tid & 63, l15 = lane & 15, lq = lane >> 4;
    const int wid = tid >> 6;
    const int wm = (wid >> 1) * 64, wn = (wid & 1) * 64;

    f32x4 acc[4][4] = {};

    const int srow = tid >> 1;
    const int sc0 = (tid & 1) * 4;
    const bf16* __restrict__ Arow = A + (size_t)(m0 + srow) * 768;
    const bf16* __restrict__ Brow = Bt + (size_t)(n0 + srow) * 768;
    const int swz = srow & 7;

    for (int ks = 0; ks < 768; ks += 64) {
#pragma unroll
        for (int i = 0; i < 4; ++i) {
            int c = sc0 + i;
            bf16x8 av = *(const bf16x8*)(Arow + ks + c * 8);
            bf16x8 bv = *(const bf16x8*)(Brow + ks + c * 8);
            int sc = c ^ swz;
            *(bf16x8*)(As + srow * 64 + sc * 8) = av;
            *(bf16x8*)(Bs + srow * 64 + sc * 8) = bv;
        }
        __syncthreads();
#pragma unroll
        for (int kk = 0; kk < 2; ++kk) {
            bf16x8 af[4], bfr[4];
#pragma unroll
            for (int f = 0; f < 4; ++f) {
                int ar = wm + f * 16 + l15;
                int ac = (kk * 4 + lq) ^ (ar & 7);
                af[f] = *(const bf16x8*)(As + ar * 64 + ac * 8);
                int br = wn + f * 16 + l15;
                int bc = (kk * 4 + lq) ^ (br & 7);
                bfr[f] = *(const bf16x8*)(Bs + br * 64 + bc * 8);
            }
#pragma unroll
            for (int mf = 0; mf < 4; ++mf)
#pragma unroll
                for (int nf = 0; nf < 4; ++nf)
                    acc[mf][nf] = __builtin_amdgcn_mfma_f32_16x16x32_bf16(af[mf], bfr[nf], acc[mf][nf], 0, 0, 0);
        }
        __syncthreads();
    }
    const float* __restrict__ bias = ga.bias[z];
#pragma unroll
    for (int nf = 0; nf < 4; ++nf) {
        int col = n0 + wn + nf * 16 + l15;
        float bv = bias[col];
#pragma unroll
        for (int mf = 0; mf < 4; ++mf) {
            int rbase = m0 + wm + mf * 16 + lq * 4;
#pragma unroll
            for (int i = 0; i < 4; ++i) {
                float v = acc[mf][nf][i] + bv;
                if constexpr (F32OUT)
                    ((float*)ga.out[z])[(size_t)(rbase + i) * 768 + col] = v;
                else
                    ((bf16*)ga.out[z])[(size_t)(rbase + i) * 768 + col] = (bf16)v;
            }
        }
    }
}

// ---------------- V transpose per head-group: V[g][kv][d] -> Vt[g][d][kv] ----------------
__global__ __launch_bounds__(256) void transpose_v(const bf16* __restrict__ V, bf16* __restrict__ Vt) {
    __shared__ unsigned short t[64 * 97];
    const int g = blockIdx.y;
    const int kv0 = blockIdx.x * 64;
    const unsigned short* __restrict__ Vg = (const unsigned short*)V + (size_t)g * 98304;
    unsigned short* __restrict__ Vtg = (unsigned short*)Vt + (size_t)g * 98304;
    const int tid = threadIdx.x;
#pragma unroll
    for (int p = 0; p < 24; ++p) {
        int id = tid + p * 256;
        int row = id / 96, col = id % 96;
        t[row * 97 + col] = Vg[(size_t)(kv0 + row) * 96 + col];
    }
    __syncthreads();
#pragma unroll
    for (int p = 0; p < 24; ++p) {
        int id = tid + p * 256;
        int d = id >> 6, j = id & 63;
        Vtg[(size_t)d * 1024 + kv0 + j] = t[j * 97 + d];
    }
}

// ---------------- helpers for in-register P ----------------
static __device__ inline int pk2(float a, float b) {
    union { __bf16 h[2]; int w; } u;
    u.h[0] = (__bf16)a; u.h[1] = (__bf16)b;
    return u.w;
}

static __device__ inline bf16x8 pack_step(float p0, float p1, float p2, float p3,
                                          float p4, float p5, float p6, float p7, int hi) {
    int A0 = pk2(p0, p1), A1 = pk2(p2, p3);
    int B0 = pk2(p4, p5), B1 = pk2(p6, p7);
    int t0 = hi ? A0 : B0;
    int t1 = hi ? A1 : B1;
    int x0 = __shfl_xor(t0, 32);
    int x1 = __shfl_xor(t1, 32);
    union { int w[4]; bf16x8 v; } u;
    u.w[0] = hi ? x0 : A0;
    u.w[1] = hi ? x1 : A1;
    u.w[2] = hi ? B0 : x0;
    u.w[3] = hi ? B1 : x1;
    return u.v;
}

// ---------------- fused flash attention, swapped-QK^T, LDS-staged K/V ----------------
// Q,K: [g][1024][96] bf16. Vt: [g][96][1024]. Out: [g][1024][96].
// 4 waves/block, 128 q-rows/block, kv-tile=64. K/V cooperatively staged into LDS
// (single-buffered, T14 async split: issue next tile's loads right after the barrier,
// ds_write them at the top of the next iteration). XOR chunk-swizzle on both tiles.
// Grid (g fast, qb slow) so a group's q-blocks share an XCD L2.
__global__ __launch_bounds__(256, 3) void attn_kernel(const bf16* __restrict__ Q, const bf16* __restrict__ K,
                                                      const bf16* __restrict__ Vt, bf16* __restrict__ AO) {
    __shared__ __align__(16) bf16 Ks[64 * 128];   // 64 kv-rows x 16 chunk-slots (12 used)
    __shared__ __align__(16) bf16 Vs[96 * 64];    // 96 d-rows x 8 chunk-slots
    const int g = blockIdx.x;
    const int q0 = blockIdx.y * 128;
    const int tid = threadIdx.x;
    const int lane = tid & 63;
    const int l31 = lane & 31;
    const int hi = lane >> 5;
    const int wid = tid >> 6;
    const int qrow = q0 + wid * 32 + l31;
    const int sw = l31 & 7;
    const size_t gbase = (size_t)g * 98304;
    const bf16* __restrict__ Qg = Q + gbase;
    const bf16* __restrict__ Kg = K + gbase;
    const bf16* __restrict__ Vg = Vt + gbase;  // [96][1024]
    bf16* __restrict__ Og = AO + gbase;

    // staging maps: 768 16B-chunks each for K (64x12) and V (96x8); 3 per thread
    int koff[3], kld[3], voff[3], vld[3];
#pragma unroll
    for (int i = 0; i < 3; ++i) {
        int id = tid + i * 256;
        int kr = id / 12, kc = id - kr * 12;
        koff[i] = kr * 96 + kc * 8;
        kld[i] = kr * 128 + (kc ^ (kr & 7)) * 8;
        int vr = id >> 3, vc = id & 7;
        voff[i] = vr * 1024 + vc * 8;
        vld[i] = vr * 64 + (vc ^ (vr & 7)) * 8;
    }

    // Q as B-fragments: qf[kk], k = kk*16 + hi*8 + j
    bf16x8 qf[6];
#pragma unroll
    for (int kk = 0; kk < 6; ++kk)
        qf[kk] = *(const bf16x8*)(Qg + (size_t)qrow * 96 + kk * 16 + hi * 8);

    f32x16 o[3] = {};
    float mrun = -INFINITY, lrun = 0.f;

    // prologue: issue tile 0 loads
    bf16x8 kst[3], vst[3];
#pragma unroll
    for (int i = 0; i < 3; ++i) {
        kst[i] = *(const bf16x8*)(Kg + koff[i]);
        vst[i] = *(const bf16x8*)(Vg + voff[i]);
    }

    for (int kt = 0; kt < 16; ++kt) {
        __syncthreads();  // all waves done reading LDS (previous tile)
#pragma unroll
        for (int i = 0; i < 3; ++i) {
            *(bf16x8*)(Ks + kld[i]) = kst[i];
            *(bf16x8*)(Vs + vld[i]) = vst[i];
        }
        __syncthreads();  // tile visible
        if (kt < 15) {
            const int kvn = (kt + 1) * 64;
#pragma unroll
            for (int i = 0; i < 3; ++i) {
                kst[i] = *(const bf16x8*)(Kg + (size_t)kvn * 96 + koff[i]);
                vst[i] = *(const bf16x8*)(Vg + kvn + voff[i]);
            }
        }

        // S^T = K @ Q^T from LDS
        f32x16 s0 = {}, s1 = {};
#pragma unroll
        for (int kk = 0; kk < 6; ++kk) {
            int slot = ((kk * 2 + hi) ^ sw) * 8;
            bf16x8 k0 = *(const bf16x8*)(Ks + l31 * 128 + slot);
            bf16x8 k1 = *(const bf16x8*)(Ks + (l31 + 32) * 128 + slot);
            s0 = __builtin_amdgcn_mfma_f32_32x32x16_bf16(k0, qf[kk], s0, 0, 0, 0);
            s1 = __builtin_amdgcn_mfma_f32_32x32x16_bf16(k1, qf[kk], s1, 0, 0, 0);
        }
        // online softmax (lane-local + one lane^32 exchange)
        float mx = s0[0];
#pragma unroll
        for (int r = 1; r < 16; ++r) mx = fmaxf(mx, s0[r]);
#pragma unroll
        for (int r = 0; r < 16; ++r) mx = fmaxf(mx, s1[r]);
        mx = fmaxf(mx, __shfl_xor(mx, 32));
        float newm = fmaxf(mrun, mx);
        float alpha = __builtin_amdgcn_exp2f(CE * (mrun - newm));
        mrun = newm;
        float lsum = 0.f;
#pragma unroll
        for (int r = 0; r < 16; ++r) {
            float p = __builtin_amdgcn_exp2f(CE * (s0[r] - newm));
            s0[r] = p; lsum += p;
        }
#pragma unroll
        for (int r = 0; r < 16; ++r) {
            float p = __builtin_amdgcn_exp2f(CE * (s1[r] - newm));
            s1[r] = p; lsum += p;
        }
        lsum += __shfl_xor(lsum, 32);
        lrun = lrun * alpha + lsum;
#pragma unroll
        for (int df = 0; df < 3; ++df)
#pragma unroll
            for (int r = 0; r < 16; ++r) o[df][r] *= alpha;

        // P packed in-register, O^T += V^T @ P^T from LDS
        bf16x8 pb0 = pack_step(s0[0], s0[1], s0[2], s0[3], s0[4], s0[5], s0[6], s0[7], hi);
        bf16x8 pb1 = pack_step(s0[8], s0[9], s0[10], s0[11], s0[12], s0[13], s0[14], s0[15], hi);
        bf16x8 pb2 = pack_step(s1[0], s1[1], s1[2], s1[3], s1[4], s1[5], s1[6], s1[7], hi);
        bf16x8 pb3 = pack_step(s1[8], s1[9], s1[10], s1[11], s1[12], s1[13], s1[14], s1[15], hi);
#pragma unroll
        for (int df = 0; df < 3; ++df) {
            const bf16* vrow = Vs + (df * 32 + l31) * 64;
            bf16x8 v0 = *(const bf16x8*)(vrow + ((0 + hi) ^ sw) * 8);
            bf16x8 v1 = *(const bf16x8*)(vrow + ((2 + hi) ^ sw) * 8);
            bf16x8 v2 = *(const bf16x8*)(vrow + ((4 + hi) ^ sw) * 8);
            bf16x8 v3 = *(const bf16x8*)(vrow + ((6 + hi) ^ sw) * 8);
            o[df] = __builtin_amdgcn_mfma_f32_32x32x16_bf16(v0, pb0, o[df], 0, 0, 0);
            o[df] = __builtin_amdgcn_mfma_f32_32x32x16_bf16(v1, pb1, o[df], 0, 0, 0);
            o[df] = __builtin_amdgcn_mfma_f32_32x32x16_bf16(v2, pb2, o[df], 0, 0, 0);
            o[df] = __builtin_amdgcn_mfma_f32_32x32x16_bf16(v3, pb3, o[df], 0, 0, 0);
        }
    }

    // epilogue
    float inv = 1.0f / lrun;
#pragma unroll
    for (int df = 0; df < 3; ++df)
#pragma unroll
        for (int rq = 0; rq < 4; ++rq) {
            bf16x4 ov;
#pragma unroll
            for (int j = 0; j < 4; ++j) ov[j] = (bf16)(o[df][rq * 4 + j] * inv);
            *(bf16x4*)(Og + (size_t)qrow * 96 + df * 32 + rq * 8 + hi * 4) = ov;
        }
}

// ---------------- launch ----------------
extern "C" void kernel_launch(void* const* d_in, const int* in_sizes, int n_in,
                              void* d_out, int out_size, void* d_ws, size_t ws_size,
                              hipStream_t stream) {
    const float* x  = (const float*)d_in[0];
    const float* Wq = (const float*)d_in[1];
    const float* bq = (const float*)d_in[2];
    const float* Wk = (const float*)d_in[3];
    const float* bk = (const float*)d_in[4];
    const float* Wv = (const float*)d_in[5];
    const float* bv = (const float*)d_in[6];
    const float* Wp = (const float*)d_in[7];
    const float* bp = (const float*)d_in[8];

    char* ws = (char*)d_ws;
    bf16* xb  = (bf16*)(ws);                  // reused as AO after QKV GEMM
    bf16* wt  = (bf16*)(ws + 25165824);       // 4 x 1,179,648 B
    bf16* Qb  = (bf16*)(ws + 29884416);
    bf16* Kb  = (bf16*)(ws + 55050240);
    bf16* Vb  = (bf16*)(ws + 80216064);
    bf16* Vtb = (bf16*)(ws + 105381888);
    bf16* AO  = xb;

    cvt_x<<<12288, 256, 0, stream>>>(x, xb);

    WArgs wa;
    wa.w[0] = Wq; wa.w[1] = Wk; wa.w[2] = Wv; wa.w[3] = Wp;
    transpose_w<<<dim3(24, 24, 4), dim3(32, 8), 0, stream>>>(wa, wt);

    GemmArgs g1{};
    g1.Bt[0] = wt;            g1.Bt[1] = wt + 589824;  g1.Bt[2] = wt + 2 * 589824;
    g1.bias[0] = bq;          g1.bias[1] = bk;         g1.bias[2] = bv;
    g1.out[0] = Qb;           g1.out[1] = Kb;          g1.out[2] = Vb;
    gemm_kernel<false><<<dim3(128, 6, 3), 256, 0, stream>>>(xb, g1);

    transpose_v<<<dim3(16, 128), 256, 0, stream>>>(Vb, Vtb);

    attn_kernel<<<dim3(128, 8), 256, 0, stream>>>(Qb, Kb, Vtb, AO);

    GemmArgs g2{};
    g2.Bt[0] = wt + 3 * 589824; g2.bias[0] = bp; g2.out[0] = (void*)d_out;
    g2.Bt[1] = g2.Bt[0]; g2.Bt[2] = g2.Bt[0];
    g2.bias[1] = bp; g2.bias[2] = bp;
    g2.out[1] = g2.out[0]; g2.out[2] = g2.out[0];
    gemm_kernel<true><<<dim3(128, 6, 1), 256, 0, stream>>>(AO, g2);
}

// Round 4
// 197.175 us; speedup vs baseline: 1.5098x; 1.1612x over previous
//
#include <hip/hip_runtime.h>
#include <math.h>

typedef __bf16 bf16;
typedef __attribute__((ext_vector_type(8))) __bf16 bf16x8;
typedef __attribute__((ext_vector_type(4))) __bf16 bf16x4;
typedef __attribute__((ext_vector_type(4))) float f32x4;
typedef __attribute__((ext_vector_type(16))) float f32x16;

#define CE 0.14724445f      /* (1/sqrt(96)) * log2(e) */
#define THR_RAW 54.0f       /* defer-max threshold in raw-logit units: CE*54 ~= 8 */

#define GLOAD16(g, l)                                                          \
    __builtin_amdgcn_global_load_lds(                                          \
        (const __attribute__((address_space(1))) void*)(g),                    \
        (__attribute__((address_space(3))) void*)(l), 16, 0, 0)

// ---------------- convert x: f32 -> bf16 ----------------
__global__ __launch_bounds__(256) void cvt_x(const float* __restrict__ x, bf16* __restrict__ xb) {
    size_t i = ((size_t)blockIdx.x * 256 + threadIdx.x) * 4;
    f32x4 v = *(const f32x4*)(x + i);
    bf16x4 o;
    o[0] = (bf16)v[0]; o[1] = (bf16)v[1]; o[2] = (bf16)v[2]; o[3] = (bf16)v[3];
    *(bf16x4*)(xb + i) = o;
}

// ---------------- transpose + convert weights: W (K,N) f32 -> Wt (N,K) bf16 ----------------
struct WArgs { const float* w[4]; };

__global__ __launch_bounds__(256) void transpose_w(WArgs wa, bf16* __restrict__ out) {
    __shared__ float t[32][33];
    const int z = blockIdx.z;
    const float* __restrict__ W = wa.w[z];
    bf16* __restrict__ Wt = out + (size_t)z * 589824;
    int k0 = blockIdx.x * 32, n0 = blockIdx.y * 32;
    int tx = threadIdx.x, ty = threadIdx.y; // 32 x 8
#pragma unroll
    for (int j = 0; j < 4; ++j)
        t[ty + j * 8][tx] = W[(size_t)(k0 + ty + j * 8) * 768 + n0 + tx];
    __syncthreads();
#pragma unroll
    for (int j = 0; j < 4; ++j)
        Wt[(size_t)(n0 + ty + j * 8) * 768 + k0 + tx] = (bf16)t[tx][ty + j * 8];
}

// ---------------- GEMM: C[M,768] = A[M,768](bf16) @ W[768,768] + bias ----------------
// m97-structure: 128x128 tile, BK=64, global_load_lds(16) staging with pre-swizzled
// source (linear LDS dest, chunk = slot ^ (row&7)), 2 barriers/K-step.
// 1-D grid, XCD-chunked swizzle, n-fastest logical order (A-panel L2 reuse per XCD).
struct GemmArgs {
    const bf16* Bt[3];
    const float* bias[3];
    void* out[3];
};

template <bool F32OUT>
__global__ __launch_bounds__(256, 2) void gemm_kernel(const bf16* __restrict__ A, GemmArgs ga) {
    __shared__ __align__(16) bf16 As[128 * 64];
    __shared__ __align__(16) bf16 Bs[128 * 64];
    const int nwg = gridDim.x;
    const int bid = blockIdx.x;
    const int lid = (bid & 7) * (nwg >> 3) + (bid >> 3);  // XCD-chunked (nwg%8==0)
    const int z = lid / 768;
    const int rem = lid - z * 768;
    const int m0 = (rem / 6) * 128;
    const int n0 = (rem % 6) * 128;
    const bf16* __restrict__ Bt = ga.Bt[z];
    const int tid = threadIdx.x;
    const int lane = tid & 63, l15 = lane & 15, lq = lane >> 4;
    const int wid = tid >> 6;
    const int wm = (wid >> 1) * 64, wn = (wid & 1) * 64;

    // staging maps: 4 A-issues + 4 B-issues per wave, 1KB each
    const bf16* asrc[4]; const bf16* bsrc[4]; bf16* adst[4]; bf16* bdst[4];
#pragma unroll
    for (int i = 0; i < 4; ++i) {
        int r = (wid * 4 + i) * 8 + (lane >> 3);   // row 0..127
        int s = lane & 7;
        int c = s ^ (r & 7);                        // pre-swizzled source chunk
        asrc[i] = A + (size_t)(m0 + r) * 768 + c * 8;
        bsrc[i] = Bt + (size_t)(n0 + r) * 768 + c * 8;
        adst[i] = As + (wid * 4 + i) * 512;         // wave-uniform dest
        bdst[i] = Bs + (wid * 4 + i) * 512;
    }

    f32x4 acc[4][4] = {};

    for (int ks = 0; ks < 768; ks += 64) {
#pragma unroll
        for (int i = 0; i < 4; ++i) {
            GLOAD16(asrc[i] + ks, adst[i]);
            GLOAD16(bsrc[i] + ks, bdst[i]);
        }
        __syncthreads();  // drains gloads + visibility
#pragma unroll
        for (int kk = 0; kk < 2; ++kk) {
            bf16x8 af[4], bfr[4];
#pragma unroll
            for (int f = 0; f < 4; ++f) {
                int ar = wm + f * 16 + l15;
                int ac = (kk * 4 + lq) ^ (ar & 7);
                af[f] = *(const bf16x8*)(As + ar * 64 + ac * 8);
                int br = wn + f * 16 + l15;
                int bc = (kk * 4 + lq) ^ (br & 7);
                bfr[f] = *(const bf16x8*)(Bs + br * 64 + bc * 8);
            }
#pragma unroll
            for (int mf = 0; mf < 4; ++mf)
#pragma unroll
                for (int nf = 0; nf < 4; ++nf)
                    acc[mf][nf] = __builtin_amdgcn_mfma_f32_16x16x32_bf16(af[mf], bfr[nf], acc[mf][nf], 0, 0, 0);
        }
        __syncthreads();  // done reading before next tile's writes
    }
    const float* __restrict__ bias = ga.bias[z];
#pragma unroll
    for (int nf = 0; nf < 4; ++nf) {
        int col = n0 + wn + nf * 16 + l15;
        float bv = bias[col];
#pragma unroll
        for (int mf = 0; mf < 4; ++mf) {
            int rbase = m0 + wm + mf * 16 + lq * 4;
#pragma unroll
            for (int i = 0; i < 4; ++i) {
                float v = acc[mf][nf][i] + bv;
                if constexpr (F32OUT)
                    ((float*)ga.out[z])[(size_t)(rbase + i) * 768 + col] = v;
                else
                    ((bf16*)ga.out[z])[(size_t)(rbase + i) * 768 + col] = (bf16)v;
            }
        }
    }
}

// ---------------- V transpose per head-group: V[g][kv][d] -> Vt[g][d][kv] ----------------
__global__ __launch_bounds__(256) void transpose_v(const bf16* __restrict__ V, bf16* __restrict__ Vt) {
    __shared__ unsigned short t[64 * 97];
    const int g = blockIdx.y;
    const int kv0 = blockIdx.x * 64;
    const unsigned short* __restrict__ Vg = (const unsigned short*)V + (size_t)g * 98304;
    unsigned short* __restrict__ Vtg = (unsigned short*)Vt + (size_t)g * 98304;
    const int tid = threadIdx.x;
#pragma unroll
    for (int p = 0; p < 24; ++p) {
        int id = tid + p * 256;
        int row = id / 96, col = id % 96;
        t[row * 97 + col] = Vg[(size_t)(kv0 + row) * 96 + col];
    }
    __syncthreads();
#pragma unroll
    for (int p = 0; p < 24; ++p) {
        int id = tid + p * 256;
        int d = id >> 6, j = id & 63;
        Vtg[(size_t)d * 1024 + kv0 + j] = t[j * 97 + d];
    }
}

// ---------------- helpers for in-register P ----------------
static __device__ inline int pk2(float a, float b) {
    union { __bf16 h[2]; int w; } u;
    u.h[0] = (__bf16)a; u.h[1] = (__bf16)b;
    return u.w;
}

static __device__ inline bf16x8 pack_step(float p0, float p1, float p2, float p3,
                                          float p4, float p5, float p6, float p7, int hi) {
    int A0 = pk2(p0, p1), A1 = pk2(p2, p3);
    int B0 = pk2(p4, p5), B1 = pk2(p6, p7);
    int t0 = hi ? A0 : B0;
    int t1 = hi ? A1 : B1;
    int x0 = __shfl_xor(t0, 32);
    int x1 = __shfl_xor(t1, 32);
    union { int w[4]; bf16x8 v; } u;
    u.w[0] = hi ? x0 : A0;
    u.w[1] = hi ? x1 : A1;
    u.w[2] = hi ? B0 : x0;
    u.w[3] = hi ? B1 : x1;
    return u.v;
}

// ---------------- fused flash attention ----------------
// Swapped QK^T (lane owns a q-row), in-register P, K single-buffered LDS +
// V double-buffered LDS, all staging via global_load_lds(16) with pre-swizzled
// sources. 2 barriers/tile, every load issued ~half a tile before its drain.
// Defer-max (T13), setprio around MFMA clusters (T5).
__global__ __launch_bounds__(256, 3) void attn_kernel(const bf16* __restrict__ Q, const bf16* __restrict__ K,
                                                      const bf16* __restrict__ Vt, bf16* __restrict__ AO) {
    __shared__ __align__(16) bf16 Ks[64 * 128];     // 16 KB: 64 rows x 16 slots (12 used)
    __shared__ __align__(16) bf16 Vss[2 * 96 * 64]; // 2 x 12 KB: 96 rows x 8 slots
    const int g = blockIdx.x;
    const int q0 = blockIdx.y * 128;
    const int tid = threadIdx.x;
    const int lane = tid & 63;
    const int l31 = lane & 31, hi = lane >> 5, wid = tid >> 6;
    const int sw = l31 & 7;
    const int qrow = q0 + wid * 32 + l31;
    const size_t gbase = (size_t)g * 98304;
    const bf16* __restrict__ Qg = Q + gbase;
    const bf16* __restrict__ Kg = K + gbase;
    const bf16* __restrict__ Vg = Vt + gbase;  // [96][1024]
    bf16* __restrict__ Og = AO + gbase;

    // K staging: 4 issues/wave (16 KB / 1 KB / 4 waves)
    const bf16* ksrc[4]; bf16* kdst[4];
#pragma unroll
    for (int i = 0; i < 4; ++i) {
        int r = (wid * 4 + i) * 4 + (lane >> 4);   // kv-row 0..63
        int s = lane & 15;
        int c = s ^ (r & 7);                        // source chunk (>=12 -> benign garbage)
        ksrc[i] = Kg + r * 96 + c * 8;
        kdst[i] = Ks + (wid * 4 + i) * 512;
    }
    // V staging: 3 issues/wave (12 KB)
    const bf16* vsrc[3]; int vdoff[3];
#pragma unroll
    for (int i = 0; i < 3; ++i) {
        int r = (wid * 3 + i) * 8 + (lane >> 3);   // d-row 0..95
        int s = lane & 7;
        int c = s ^ (r & 7);
        vsrc[i] = Vg + (size_t)r * 1024 + c * 8;
        vdoff[i] = (wid * 3 + i) * 512;
    }

    // Q as B-fragments: qf[kk], k = kk*16 + hi*8 + j
    bf16x8 qf[6];
#pragma unroll
    for (int kk = 0; kk < 6; ++kk)
        qf[kk] = *(const bf16x8*)(Qg + (size_t)qrow * 96 + kk * 16 + hi * 8);

    // prologue: K(0), V(0); drain; then V(1) in flight
#pragma unroll
    for (int i = 0; i < 4; ++i) GLOAD16(ksrc[i], kdst[i]);
#pragma unroll
    for (int i = 0; i < 3; ++i) GLOAD16(vsrc[i], Vss + vdoff[i]);
    __syncthreads();
#pragma unroll
    for (int i = 0; i < 3; ++i) GLOAD16(vsrc[i] + 64, Vss + 6144 + vdoff[i]);

    f32x16 o[3] = {};
    float mrun = -INFINITY, lrun = 0.f;

    for (int kt = 0; kt < 16; ++kt) {
        const bf16* Vcur = Vss + (kt & 1) * 6144;

        // S^T = K @ Q^T from Ks
        f32x16 s0 = {}, s1 = {};
        __builtin_amdgcn_s_setprio(1);
#pragma unroll
        for (int kk = 0; kk < 6; ++kk) {
            int slot = ((kk * 2 + hi) ^ sw) * 8;
            bf16x8 k0 = *(const bf16x8*)(Ks + l31 * 128 + slot);
            bf16x8 k1 = *(const bf16x8*)(Ks + (l31 + 32) * 128 + slot);
            s0 = __builtin_amdgcn_mfma_f32_32x32x16_bf16(k0, qf[kk], s0, 0, 0, 0);
            s1 = __builtin_amdgcn_mfma_f32_32x32x16_bf16(k1, qf[kk], s1, 0, 0, 0);
        }
        __builtin_amdgcn_s_setprio(0);
        __syncthreads();  // bar1: all waves done reading Ks; drains V(t+1)
        if (kt < 15) {
#pragma unroll
            for (int i = 0; i < 4; ++i) GLOAD16(ksrc[i] + (kt + 1) * 6144, kdst[i]);
        }

        // online softmax with defer-max
        float t0 = fmaxf(fmaxf(s0[0], s0[1]), fmaxf(s0[2], s0[3]));
        float t1 = fmaxf(fmaxf(s0[4], s0[5]), fmaxf(s0[6], s0[7]));
        float t2 = fmaxf(fmaxf(s0[8], s0[9]), fmaxf(s0[10], s0[11]));
        float t3 = fmaxf(fmaxf(s0[12], s0[13]), fmaxf(s0[14], s0[15]));
        float u0 = fmaxf(fmaxf(s1[0], s1[1]), fmaxf(s1[2], s1[3]));
        float u1 = fmaxf(fmaxf(s1[4], s1[5]), fmaxf(s1[6], s1[7]));
        float u2 = fmaxf(fmaxf(s1[8], s1[9]), fmaxf(s1[10], s1[11]));
        float u3 = fmaxf(fmaxf(s1[12], s1[13]), fmaxf(s1[14], s1[15]));
        float pmax = fmaxf(fmaxf(fmaxf(t0, t1), fmaxf(t2, t3)),
                           fmaxf(fmaxf(u0, u1), fmaxf(u2, u3)));
        pmax = fmaxf(pmax, __shfl_xor(pmax, 32));
        if (!__all(pmax - mrun <= THR_RAW)) {
            float newm = fmaxf(mrun, pmax);
            float alpha = __builtin_amdgcn_exp2f(CE * (mrun - newm));
            mrun = newm;
            lrun *= alpha;
#pragma unroll
            for (int df = 0; df < 3; ++df)
#pragma unroll
                for (int r = 0; r < 16; ++r) o[df][r] *= alpha;
        }
        float lsa = 0.f, lsb = 0.f;
#pragma unroll
        for (int r = 0; r < 16; ++r) {
            float p = __builtin_amdgcn_exp2f(CE * (s0[r] - mrun));
            s0[r] = p; lsa += p;
        }
#pragma unroll
        for (int r = 0; r < 16; ++r) {
            float p = __builtin_amdgcn_exp2f(CE * (s1[r] - mrun));
            s1[r] = p; lsb += p;
        }
        float lsum = lsa + lsb;
        lsum += __shfl_xor(lsum, 32);
        lrun += lsum;

        // P packed in-register, O^T += V^T @ P^T from Vcur
        bf16x8 pb0 = pack_step(s0[0], s0[1], s0[2], s0[3], s0[4], s0[5], s0[6], s0[7], hi);
        bf16x8 pb1 = pack_step(s0[8], s0[9], s0[10], s0[11], s0[12], s0[13], s0[14], s0[15], hi);
        bf16x8 pb2 = pack_step(s1[0], s1[1], s1[2], s1[3], s1[4], s1[5], s1[6], s1[7], hi);
        bf16x8 pb3 = pack_step(s1[8], s1[9], s1[10], s1[11], s1[12], s1[13], s1[14], s1[15], hi);
        __builtin_amdgcn_s_setprio(1);
#pragma unroll
        for (int df = 0; df < 3; ++df) {
            const bf16* vrow = Vcur + (df * 32 + l31) * 64;
            bf16x8 v0 = *(const bf16x8*)(vrow + ((0 + hi) ^ sw) * 8);
            bf16x8 v1 = *(const bf16x8*)(vrow + ((2 + hi) ^ sw) * 8);
            bf16x8 v2 = *(const bf16x8*)(vrow + ((4 + hi) ^ sw) * 8);
            bf16x8 v3 = *(const bf16x8*)(vrow + ((6 + hi) ^ sw) * 8);
            o[df] = __builtin_amdgcn_mfma_f32_32x32x16_bf16(v0, pb0, o[df], 0, 0, 0);
            o[df] = __builtin_amdgcn_mfma_f32_32x32x16_bf16(v1, pb1, o[df], 0, 0, 0);
            o[df] = __builtin_amdgcn_mfma_f32_32x32x16_bf16(v2, pb2, o[df], 0, 0, 0);
            o[df] = __builtin_amdgcn_mfma_f32_32x32x16_bf16(v3, pb3, o[df], 0, 0, 0);
        }
        __builtin_amdgcn_s_setprio(0);
        __syncthreads();  // bar2: drains K(t+1); all waves done reading Vcur
        if (kt < 14) {
#pragma unroll
            for (int i = 0; i < 3; ++i)
                GLOAD16(vsrc[i] + (kt + 2) * 64, Vss + (kt & 1) * 6144 + vdoff[i]);
        }
    }

    // epilogue: O[q][d] = O^T[d][q] / lrun
    float inv = 1.0f / lrun;
#pragma unroll
    for (int df = 0; df < 3; ++df)
#pragma unroll
        for (int rq = 0; rq < 4; ++rq) {
            bf16x4 ov;
#pragma unroll
            for (int j = 0; j < 4; ++j) ov[j] = (bf16)(o[df][rq * 4 + j] * inv);
            *(bf16x4*)(Og + (size_t)qrow * 96 + df * 32 + rq * 8 + hi * 4) = ov;
        }
}

// ---------------- launch ----------------
extern "C" void kernel_launch(void* const* d_in, const int* in_sizes, int n_in,
                              void* d_out, int out_size, void* d_ws, size_t ws_size,
                              hipStream_t stream) {
    const float* x  = (const float*)d_in[0];
    const float* Wq = (const float*)d_in[1];
    const float* bq = (const float*)d_in[2];
    const float* Wk = (const float*)d_in[3];
    const float* bk = (const float*)d_in[4];
    const float* Wv = (const float*)d_in[5];
    const float* bv = (const float*)d_in[6];
    const float* Wp = (const float*)d_in[7];
    const float* bp = (const float*)d_in[8];

    char* ws = (char*)d_ws;
    bf16* xb  = (bf16*)(ws);                  // reused as AO after QKV GEMM
    bf16* wt  = (bf16*)(ws + 25165824);       // 4 x 1,179,648 B
    bf16* Qb  = (bf16*)(ws + 29884416);
    bf16* Kb  = (bf16*)(ws + 55050240);
    bf16* Vb  = (bf16*)(ws + 80216064);
    bf16* Vtb = (bf16*)(ws + 105381888);
    bf16* AO  = xb;

    cvt_x<<<12288, 256, 0, stream>>>(x, xb);

    WArgs wa;
    wa.w[0] = Wq; wa.w[1] = Wk; wa.w[2] = Wv; wa.w[3] = Wp;
    transpose_w<<<dim3(24, 24, 4), dim3(32, 8), 0, stream>>>(wa, wt);

    GemmArgs g1{};
    g1.Bt[0] = wt;            g1.Bt[1] = wt + 589824;  g1.Bt[2] = wt + 2 * 589824;
    g1.bias[0] = bq;          g1.bias[1] = bk;         g1.bias[2] = bv;
    g1.out[0] = Qb;           g1.out[1] = Kb;          g1.out[2] = Vb;
    gemm_kernel<false><<<2304, 256, 0, stream>>>(xb, g1);

    transpose_v<<<dim3(16, 128), 256, 0, stream>>>(Vb, Vtb);

    attn_kernel<<<dim3(128, 8), 256, 0, stream>>>(Qb, Kb, Vtb, AO);

    GemmArgs g2{};
    g2.Bt[0] = wt + 3 * 589824; g2.bias[0] = bp; g2.out[0] = (void*)d_out;
    g2.Bt[1] = g2.Bt[0]; g2.Bt[2] = g2.Bt[0];
    g2.bias[1] = bp; g2.bias[2] = bp;
    g2.out[1] = g2.out[0]; g2.out[2] = g2.out[0];
    gemm_kernel<true><<<768, 256, 0, stream>>>(AO, g2);
}